// Round 6
// baseline (431.747 us; speedup 1.0000x reference)
//
#include <hip/hip_runtime.h>
#include <hip/hip_bf16.h>

#define N_NODES 50000
#define N_EDGES 800000
#define NB_SCAN 196    // ceil(50000/256)
#define NBLK_H  100    // histogram/fill partitions
#define BINS    500    // bins per partition (100*500 = 50000)
#define VEC8    (N_EDGES / 8)   // 100000 ushort8 elements

typedef __bf16 bf16_t;
typedef bf16_t bf16x8 __attribute__((ext_vector_type(8)));
typedef float  f32x4  __attribute__((ext_vector_type(4)));
typedef ushort ushort8 __attribute__((ext_vector_type(8)));

static __device__ __forceinline__ float bfhi_to_f(uint v) {
    return __builtin_bit_cast(float, v & 0xffff0000u);
}
static __device__ __forceinline__ float bflo_to_f(uint v) {
    return __builtin_bit_cast(float, v << 16);
}
static __device__ __forceinline__ ushort f_to_bf(float x) {
    bf16_t q = (bf16_t)x;
    return __builtin_bit_cast(ushort, q);
}

// ---------------- pack src/dst int32 -> ushort ----------------
__global__ __launch_bounds__(256) void pack_kernel(const int* __restrict__ src,
                                                   const int* __restrict__ dst,
                                                   ushort* __restrict__ s16,
                                                   ushort* __restrict__ d16) {
    int idx = (blockIdx.x * 256 + threadIdx.x) * 4;
    if (idx >= N_EDGES) return;
    int4 s = *(const int4*)(src + idx);
    int4 d = *(const int4*)(dst + idx);
    ushort4 sp, dp;
    sp.x = (ushort)s.x; sp.y = (ushort)s.y; sp.z = (ushort)s.z; sp.w = (ushort)s.w;
    dp.x = (ushort)d.x; dp.y = (ushort)d.y; dp.z = (ushort)d.z; dp.w = (ushort)d.w;
    *(ushort4*)(s16 + idx) = sp;
    *(ushort4*)(d16 + idx) = dp;
}

// ---------------- partitioned LDS histogram (no global atomics) ----------------
// blocks [0,NBLK_H): dst -> cnt_dst ; blocks [NBLK_H, 2*NBLK_H): src -> cnt_src
__global__ __launch_bounds__(512) void hist_kernel(const ushort* __restrict__ d16,
                                                   const ushort* __restrict__ s16,
                                                   int* __restrict__ cnt_dst,
                                                   int* __restrict__ cnt_src) {
    __shared__ int h[BINS];
    bool is_dst = blockIdx.x < NBLK_H;
    int part = is_dst ? blockIdx.x : (blockIdx.x - NBLK_H);
    int base = part * BINS;
    int tid = threadIdx.x;
    for (int i = tid; i < BINS; i += 512) h[i] = 0;
    __syncthreads();
    const ushort8* v = (const ushort8*)(is_dst ? d16 : s16);
    for (int i = tid; i < VEC8; i += 512) {
        ushort8 x = v[i];
#pragma unroll
        for (int j = 0; j < 8; ++j) {
            unsigned bi = (unsigned)((int)x[j] - base);
            if (bi < (unsigned)BINS) atomicAdd(&h[bi], 1);
        }
    }
    __syncthreads();
    int* cnt = is_dst ? cnt_dst : cnt_src;
    for (int i = tid; i < BINS; i += 512) cnt[base + i] = h[i];
}

// ---------------- scan1 + fused degree norms ----------------
__global__ __launch_bounds__(256) void scan1_kernel(const int* __restrict__ cnt_dst,
                                                    const int* __restrict__ cnt_src,
                                                    int* __restrict__ row_start,
                                                    int* __restrict__ blocksum,
                                                    float* __restrict__ dn_in,
                                                    float* __restrict__ dn_out) {
    __shared__ int s[256];
    int i = blockIdx.x * 256 + threadIdx.x;
    int v = (i < N_NODES) ? cnt_dst[i] : 0;
    if (i < N_NODES) {
        dn_in[i]  = 1.0f / sqrtf(fmaxf((float)v, 1.0f));
        dn_out[i] = 1.0f / sqrtf(fmaxf((float)cnt_src[i], 1.0f));
    }
    s[threadIdx.x] = v;
    __syncthreads();
    for (int off = 1; off < 256; off <<= 1) {
        int t = (threadIdx.x >= off) ? s[threadIdx.x - off] : 0;
        __syncthreads();
        s[threadIdx.x] += t;
        __syncthreads();
    }
    if (i < N_NODES) row_start[i] = s[threadIdx.x] - v;   // exclusive
    if (threadIdx.x == 255) blocksum[blockIdx.x] = s[255];
}

__global__ __launch_bounds__(256) void scan2_kernel(int* __restrict__ blocksum) {
    __shared__ int s[256];
    int v = (threadIdx.x < NB_SCAN) ? blocksum[threadIdx.x] : 0;
    s[threadIdx.x] = v;
    __syncthreads();
    for (int off = 1; off < 256; off <<= 1) {
        int t = (threadIdx.x >= off) ? s[threadIdx.x - off] : 0;
        __syncthreads();
        s[threadIdx.x] += t;
        __syncthreads();
    }
    if (threadIdx.x < NB_SCAN) blocksum[threadIdx.x] = s[threadIdx.x] - v;  // exclusive
}

__global__ __launch_bounds__(256) void scan3_kernel(int* __restrict__ row_start,
                                                    const int* __restrict__ blocksum) {
    int i = blockIdx.x * 256 + threadIdx.x;
    if (i < N_NODES) row_start[i] += blocksum[blockIdx.x];
}

// ---------------- partitioned CSR fill (LDS cursors, no global atomics) ----------------
__global__ __launch_bounds__(512) void fill_kernel(const ushort* __restrict__ d16,
                                                   const ushort* __restrict__ s16,
                                                   const int* __restrict__ row_start,
                                                   ushort* __restrict__ es16) {
    __shared__ int cur[BINS];
    int base = blockIdx.x * BINS;
    int tid = threadIdx.x;
    for (int i = tid; i < BINS; i += 512) cur[i] = row_start[base + i];
    __syncthreads();
    const ushort8* dv = (const ushort8*)d16;
    const ushort8* sv = (const ushort8*)s16;
    for (int i = tid; i < VEC8; i += 512) {
        ushort8 d8 = dv[i];
        ushort8 s8 = sv[i];
#pragma unroll
        for (int j = 0; j < 8; ++j) {
            unsigned bi = (unsigned)((int)d8[j] - base);
            if (bi < (unsigned)BINS) {
                int pos = atomicAdd(&cur[bi], 1);
                es16[pos] = s8[j];
            }
        }
    }
}

// ---------------- W1T/W2T bf16 transposed weight prep ----------------
__global__ __launch_bounds__(256) void prep_w_kernel(const float* __restrict__ W1,
                                                     const float* __restrict__ W2,
                                                     ushort* __restrict__ W1T,
                                                     ushort* __restrict__ W2T) {
    int i = blockIdx.x * 256 + threadIdx.x;
    if (i < 32768) {
        int j = i >> 8, k = i & 255;
        W1T[i] = f_to_bf(W1[k * 128 + j]);
    }
    if (i < 4096) {
        int j = i >> 7, k = i & 127;
        W2T[i] = f_to_bf(W2[k * 32 + j]);
    }
}

// ---------------- GEMM1 (MFMA): hp = bf16( (feat*dn_out) @ W1 ) ----------------
__global__ __launch_bounds__(256) void gemm1_kernel(const float* __restrict__ feat,
                                                    const ushort* __restrict__ W1T,
                                                    const float* __restrict__ dn_out,
                                                    ushort* __restrict__ hp) {
    int wave = (blockIdx.x * 256 + threadIdx.x) >> 6;
    if (wave >= 3125) return;
    int lane = threadIdx.x & 63;
    int r0 = wave * 16;
    int row = r0 + (lane & 15);
    int ksel = (lane >> 4) * 8;
    float scale = dn_out[row];
    const float* fr = feat + row * 256 + ksel;
    const bf16x8* w1 = (const bf16x8*)W1T;

    f32x4 acc[8];
#pragma unroll
    for (int jt = 0; jt < 8; ++jt) acc[jt] = (f32x4){0.f, 0.f, 0.f, 0.f};

#pragma unroll
    for (int kc = 0; kc < 8; ++kc) {
        float4 f0 = *(const float4*)(fr + kc * 32);
        float4 f1 = *(const float4*)(fr + kc * 32 + 4);
        bf16x8 a;
        a[0] = (bf16_t)(f0.x * scale); a[1] = (bf16_t)(f0.y * scale);
        a[2] = (bf16_t)(f0.z * scale); a[3] = (bf16_t)(f0.w * scale);
        a[4] = (bf16_t)(f1.x * scale); a[5] = (bf16_t)(f1.y * scale);
        a[6] = (bf16_t)(f1.z * scale); a[7] = (bf16_t)(f1.w * scale);
        int kidx = (kc * 32 + ksel) >> 3;
#pragma unroll
        for (int jt = 0; jt < 8; ++jt) {
            int j = jt * 16 + (lane & 15);
            bf16x8 b = w1[j * 32 + kidx];
            acc[jt] = __builtin_amdgcn_mfma_f32_16x16x32_bf16(a, b, acc[jt], 0, 0, 0);
        }
    }
    int rbase = r0 + (lane >> 4) * 4;
#pragma unroll
    for (int jt = 0; jt < 8; ++jt) {
        int j = jt * 16 + (lane & 15);
#pragma unroll
        for (int r = 0; r < 4; ++r) {
            hp[(rbase + r) * 128 + j] = f_to_bf(acc[jt][r]);
        }
    }
}

// ---------------- layer-1 gather-aggregate + fused epilogue (bf16) ----------------
__global__ __launch_bounds__(256) void agg1_kernel(const int* __restrict__ row_start,
                                                   const int* __restrict__ cnt_dst,
                                                   const ushort* __restrict__ es16,
                                                   const ushort* __restrict__ hp,
                                                   const float* __restrict__ dn_in,
                                                   const float* __restrict__ dn_out,
                                                   const float* __restrict__ b1,
                                                   ushort* __restrict__ h1s) {
    int wid = threadIdx.x >> 6;
    int lane = threadIdx.x & 63;
    int n = blockIdx.x * 4 + wid;
    if (n >= N_NODES) return;
    int beg = row_start[n];
    int len = cnt_dst[n];
    int c = lane * 2;
    float ax = 0.f, ay = 0.f;
    int j = 0;
    for (; j + 1 < len; j += 2) {
        int s0 = es16[beg + j];
        int s1 = es16[beg + j + 1];
        uint v0 = *(const uint*)(hp + s0 * 128 + c);
        uint v1 = *(const uint*)(hp + s1 * 128 + c);
        ax += bflo_to_f(v0) + bflo_to_f(v1);
        ay += bfhi_to_f(v0) + bfhi_to_f(v1);
    }
    if (j < len) {
        uint v0 = *(const uint*)(hp + (int)es16[beg + j] * 128 + c);
        ax += bflo_to_f(v0);
        ay += bfhi_to_f(v0);
    }
    float dn_i = dn_in[n], dn_o = dn_out[n];
    float x0 = fmaxf(ax * dn_i + b1[c], 0.f) * dn_o;
    float x1 = fmaxf(ay * dn_i + b1[c + 1], 0.f) * dn_o;
    uint pk = (uint)f_to_bf(x0) | ((uint)f_to_bf(x1) << 16);
    *(uint*)(h1s + n * 128 + c) = pk;
}

// ---------------- GEMM2 (MFMA): hp2 = bf16( h1s @ W2 ) ----------------
__global__ __launch_bounds__(256) void gemm2_kernel(const ushort* __restrict__ h1s,
                                                    const ushort* __restrict__ W2T,
                                                    ushort* __restrict__ hp2) {
    int wave = (blockIdx.x * 256 + threadIdx.x) >> 6;
    if (wave >= 3125) return;
    int lane = threadIdx.x & 63;
    int r0 = wave * 16;
    int row = r0 + (lane & 15);
    const bf16x8* av = (const bf16x8*)(h1s + row * 128);
    const bf16x8* w2 = (const bf16x8*)W2T;

    f32x4 acc[2];
    acc[0] = (f32x4){0.f, 0.f, 0.f, 0.f};
    acc[1] = (f32x4){0.f, 0.f, 0.f, 0.f};
#pragma unroll
    for (int kc = 0; kc < 4; ++kc) {
        bf16x8 a = av[kc * 4 + (lane >> 4)];
#pragma unroll
        for (int jt = 0; jt < 2; ++jt) {
            int j = jt * 16 + (lane & 15);
            bf16x8 b = w2[j * 16 + kc * 4 + (lane >> 4)];
            acc[jt] = __builtin_amdgcn_mfma_f32_16x16x32_bf16(a, b, acc[jt], 0, 0, 0);
        }
    }
    int rbase = r0 + (lane >> 4) * 4;
#pragma unroll
    for (int jt = 0; jt < 2; ++jt) {
        int j = jt * 16 + (lane & 15);
#pragma unroll
        for (int r = 0; r < 4; ++r) {
            hp2[(rbase + r) * 32 + j] = f_to_bf(acc[jt][r]);
        }
    }
}

// ---------------- layer-2 gather-aggregate + bias + log_softmax ----------------
__global__ __launch_bounds__(256) void agg2lsm_kernel(const int* __restrict__ row_start,
                                                      const int* __restrict__ cnt_dst,
                                                      const ushort* __restrict__ es16,
                                                      const ushort* __restrict__ hp2,
                                                      const float* __restrict__ dn_in,
                                                      const float* __restrict__ b2,
                                                      float* __restrict__ out) {
    int g = threadIdx.x >> 5;
    int lane = threadIdx.x & 31;
    int n = blockIdx.x * 8 + g;
    if (n >= N_NODES) return;
    int beg = row_start[n];
    int len = cnt_dst[n];
    float acc = 0.f;
    int j = 0;
    for (; j + 1 < len; j += 2) {
        int s0 = es16[beg + j];
        int s1 = es16[beg + j + 1];
        acc += bflo_to_f((uint)hp2[s0 * 32 + lane]) + bflo_to_f((uint)hp2[s1 * 32 + lane]);
    }
    if (j < len) acc += bflo_to_f((uint)hp2[(int)es16[beg + j] * 32 + lane]);
    float x = acc * dn_in[n] + b2[lane];
    float mx = x;
    for (int m = 16; m; m >>= 1) mx = fmaxf(mx, __shfl_xor(mx, m, 32));
    float ex = expf(x - mx);
    float s = ex;
    for (int m = 16; m; m >>= 1) s += __shfl_xor(s, m, 32);
    out[n * 32 + lane] = x - mx - logf(s);
}

extern "C" void kernel_launch(void* const* d_in, const int* in_sizes, int n_in,
                              void* d_out, int out_size, void* d_ws, size_t ws_size,
                              hipStream_t stream) {
    const float* feat = (const float*)d_in[0];
    const int*   src  = (const int*)d_in[1];
    const int*   dst  = (const int*)d_in[2];
    const float* W1   = (const float*)d_in[3];
    const float* b1   = (const float*)d_in[4];
    const float* W2   = (const float*)d_in[5];
    const float* b2   = (const float*)d_in[6];
    float* out = (float*)d_out;

    // workspace layout, 4-byte units (16B-aligned sections)
    int*   iws       = (int*)d_ws;
    int*   cnt_src   = iws;                 // 50000
    int*   cnt_dst   = iws + 50000;         // 50000
    int*   row_start = iws + 100000;        // 50000
    int*   blocksum  = iws + 150000;        // 256
    ushort* d16      = (ushort*)(iws + 150256);   // 800000 ushort -> ends 550256
    ushort* s16      = (ushort*)(iws + 550256);   // 800000 ushort -> ends 950256
    ushort* es16     = (ushort*)(iws + 950256);   // 800000 ushort -> ends 1350256
    float* fws       = (float*)d_ws;
    float* dn_out    = fws + 1350256;       // 50000
    float* dn_in     = fws + 1400256;       // 50000 -> ends 1450256
    ushort* W1T = (ushort*)(fws + 1450256); // 32768 bf16 -> ends 1466640
    ushort* W2T = (ushort*)(fws + 1466640); // 4096 bf16  -> ends 1468688
    ushort* hp  = (ushort*)(fws + 1468688); // 6.4M bf16  -> ends 4668688
    ushort* h1s = (ushort*)(fws + 4668688); // 6.4M bf16  -> ends 7868688
    ushort* hp2 = (ushort*)(fws + 7868688); // 1.6M bf16  -> ends 8668688 (~34.7 MB)

    pack_kernel<<<(N_EDGES / 4 + 255) / 256, 256, 0, stream>>>(src, dst, s16, d16);
    hist_kernel<<<2 * NBLK_H, 512, 0, stream>>>(d16, s16, cnt_dst, cnt_src);
    scan1_kernel<<<NB_SCAN, 256, 0, stream>>>(cnt_dst, cnt_src, row_start, blocksum,
                                              dn_in, dn_out);
    scan2_kernel<<<1, 256, 0, stream>>>(blocksum);
    scan3_kernel<<<NB_SCAN, 256, 0, stream>>>(row_start, blocksum);
    fill_kernel<<<NBLK_H, 512, 0, stream>>>(d16, s16, row_start, es16);
    prep_w_kernel<<<128, 256, 0, stream>>>(W1, W2, W1T, W2T);

    gemm1_kernel<<<(3125 * 64 + 255) / 256, 256, 0, stream>>>(feat, W1T, dn_out, hp);
    agg1_kernel<<<(N_NODES + 3) / 4, 256, 0, stream>>>(row_start, cnt_dst, es16,
                                                       hp, dn_in, dn_out, b1, h1s);
    gemm2_kernel<<<(3125 * 64 + 255) / 256, 256, 0, stream>>>(h1s, W2T, hp2);
    agg2lsm_kernel<<<(N_NODES + 7) / 8, 256, 0, stream>>>(row_start, cnt_dst, es16,
                                                          hp2, dn_in, b2, out);
}

// Round 8
// 331.044 us; speedup vs baseline: 1.3042x; 1.3042x over previous
//
#include <hip/hip_runtime.h>
#include <hip/hip_bf16.h>

#define N_NODES 50000
#define N_EDGES 800000
#define NB_SCAN 196    // ceil(50000/256)
#define REP     8      // counter replicas (one per XCD, heuristic blockIdx&7)
#define EB4     782    // ceil(200000/256) blocks for 4-edge/thread kernels

typedef __bf16 bf16_t;
typedef bf16_t bf16x8 __attribute__((ext_vector_type(8)));
typedef float  f32x4  __attribute__((ext_vector_type(4)));

static __device__ __forceinline__ float bfhi_to_f(uint v) {
    return __builtin_bit_cast(float, v & 0xffff0000u);
}
static __device__ __forceinline__ float bflo_to_f(uint v) {
    return __builtin_bit_cast(float, v << 16);
}
static __device__ __forceinline__ ushort f_to_bf(float x) {
    bf16_t q = (bf16_t)x;
    return __builtin_bit_cast(ushort, q);
}

// ---------------- pack src/dst int32 -> ushort ----------------
__global__ __launch_bounds__(256) void pack_kernel(const int* __restrict__ src,
                                                   const int* __restrict__ dst,
                                                   ushort* __restrict__ s16,
                                                   ushort* __restrict__ d16) {
    int idx = (blockIdx.x * 256 + threadIdx.x) * 4;
    if (idx >= N_EDGES) return;
    int4 s = *(const int4*)(src + idx);
    int4 d = *(const int4*)(dst + idx);
    ushort4 sp, dp;
    sp.x = (ushort)s.x; sp.y = (ushort)s.y; sp.z = (ushort)s.z; sp.w = (ushort)s.w;
    dp.x = (ushort)d.x; dp.y = (ushort)d.y; dp.z = (ushort)d.z; dp.w = (ushort)d.w;
    *(ushort4*)(s16 + idx) = sp;
    *(ushort4*)(d16 + idx) = dp;
}

// ---------------- XCD-replicated degree histograms ----------------
// replica = blockIdx & 7 -> atomics stay in one XCD's L2 (heuristic mapping)
__global__ __launch_bounds__(256) void hist_kernel(const ushort* __restrict__ d16,
                                                   const ushort* __restrict__ s16,
                                                   int* __restrict__ cntd,
                                                   int* __restrict__ cnts) {
    int idx = (blockIdx.x * 256 + threadIdx.x) * 4;
    if (idx >= N_EDGES) return;
    int r = blockIdx.x & (REP - 1);
    ushort4 d4 = *(const ushort4*)(d16 + idx);
    ushort4 s4 = *(const ushort4*)(s16 + idx);
    int* cd = cntd + r * N_NODES;
    int* cs = cnts + r * N_NODES;
    atomicAdd(&cd[d4.x], 1); atomicAdd(&cd[d4.y], 1);
    atomicAdd(&cd[d4.z], 1); atomicAdd(&cd[d4.w], 1);
    atomicAdd(&cs[s4.x], 1); atomicAdd(&cs[s4.y], 1);
    atomicAdd(&cs[s4.z], 1); atomicAdd(&cs[s4.w], 1);
}

// ---------------- scan1: replica-reduce + degree norms + block scan ----------------
__global__ __launch_bounds__(256) void scan1_kernel(const int* __restrict__ cntd,
                                                    const int* __restrict__ cnts,
                                                    int* __restrict__ deg_dst,
                                                    int* __restrict__ row_start,
                                                    int* __restrict__ blocksum,
                                                    float* __restrict__ dn_in,
                                                    float* __restrict__ dn_out) {
    __shared__ int s[256];
    int i = blockIdx.x * 256 + threadIdx.x;
    int v = 0;
    if (i < N_NODES) {
        int u = 0;
#pragma unroll
        for (int r = 0; r < REP; ++r) {
            v += cntd[r * N_NODES + i];
            u += cnts[r * N_NODES + i];
        }
        deg_dst[i] = v;
        dn_in[i]  = 1.0f / sqrtf(fmaxf((float)v, 1.0f));
        dn_out[i] = 1.0f / sqrtf(fmaxf((float)u, 1.0f));
    }
    s[threadIdx.x] = v;
    __syncthreads();
    for (int off = 1; off < 256; off <<= 1) {
        int t = (threadIdx.x >= off) ? s[threadIdx.x - off] : 0;
        __syncthreads();
        s[threadIdx.x] += t;
        __syncthreads();
    }
    if (i < N_NODES) row_start[i] = s[threadIdx.x] - v;   // exclusive
    if (threadIdx.x == 255) blocksum[blockIdx.x] = s[255];
}

__global__ __launch_bounds__(256) void scan2_kernel(int* __restrict__ blocksum) {
    __shared__ int s[256];
    int v = (threadIdx.x < NB_SCAN) ? blocksum[threadIdx.x] : 0;
    s[threadIdx.x] = v;
    __syncthreads();
    for (int off = 1; off < 256; off <<= 1) {
        int t = (threadIdx.x >= off) ? s[threadIdx.x - off] : 0;
        __syncthreads();
        s[threadIdx.x] += t;
        __syncthreads();
    }
    if (threadIdx.x < NB_SCAN) blocksum[threadIdx.x] = s[threadIdx.x] - v;  // exclusive
}

__global__ __launch_bounds__(256) void scan3_kernel(int* __restrict__ row_start,
                                                    const int* __restrict__ blocksum) {
    int i = blockIdx.x * 256 + threadIdx.x;
    if (i < N_NODES) row_start[i] += blocksum[blockIdx.x];
}

// ---------------- per-(node, replica) cursor pre-reservation ----------------
__global__ __launch_bounds__(256) void offs_kernel(const int* __restrict__ row_start,
                                                   const int* __restrict__ cntd,
                                                   int* __restrict__ offs) {
    int i = blockIdx.x * 256 + threadIdx.x;
    if (i >= N_NODES) return;
    int acc = row_start[i];
#pragma unroll
    for (int r = 0; r < REP; ++r) {
        offs[r * N_NODES + i] = acc;
        acc += cntd[r * N_NODES + i];
    }
}

// ---------------- CSR fill via replica-private cursors ----------------
__global__ __launch_bounds__(256) void fill_kernel(const ushort* __restrict__ d16,
                                                   const ushort* __restrict__ s16,
                                                   int* __restrict__ offs,
                                                   ushort* __restrict__ es16) {
    int idx = (blockIdx.x * 256 + threadIdx.x) * 4;
    if (idx >= N_EDGES) return;
    int r = blockIdx.x & (REP - 1);
    ushort4 d4 = *(const ushort4*)(d16 + idx);
    ushort4 s4 = *(const ushort4*)(s16 + idx);
    int* of = offs + r * N_NODES;
    int p;
    p = atomicAdd(&of[d4.x], 1); es16[p] = s4.x;
    p = atomicAdd(&of[d4.y], 1); es16[p] = s4.y;
    p = atomicAdd(&of[d4.z], 1); es16[p] = s4.z;
    p = atomicAdd(&of[d4.w], 1); es16[p] = s4.w;
}

// ---------------- W1T/W2T bf16 transposed weight prep ----------------
__global__ __launch_bounds__(256) void prep_w_kernel(const float* __restrict__ W1,
                                                     const float* __restrict__ W2,
                                                     ushort* __restrict__ W1T,
                                                     ushort* __restrict__ W2T) {
    int i = blockIdx.x * 256 + threadIdx.x;
    if (i < 32768) {
        int j = i >> 8, k = i & 255;
        W1T[i] = f_to_bf(W1[k * 128 + j]);
    }
    if (i < 4096) {
        int j = i >> 7, k = i & 127;
        W2T[i] = f_to_bf(W2[k * 32 + j]);
    }
}

// ---------------- GEMM1 (MFMA): hp = bf16( (feat*dn_out) @ W1 ) ----------------
__global__ __launch_bounds__(256) void gemm1_kernel(const float* __restrict__ feat,
                                                    const ushort* __restrict__ W1T,
                                                    const float* __restrict__ dn_out,
                                                    ushort* __restrict__ hp) {
    int wave = (blockIdx.x * 256 + threadIdx.x) >> 6;
    if (wave >= 3125) return;
    int lane = threadIdx.x & 63;
    int r0 = wave * 16;
    int row = r0 + (lane & 15);
    int ksel = (lane >> 4) * 8;
    float scale = dn_out[row];
    const float* fr = feat + row * 256 + ksel;
    const bf16x8* w1 = (const bf16x8*)W1T;

    f32x4 acc[8];
#pragma unroll
    for (int jt = 0; jt < 8; ++jt) acc[jt] = (f32x4){0.f, 0.f, 0.f, 0.f};

#pragma unroll
    for (int kc = 0; kc < 8; ++kc) {
        float4 f0 = *(const float4*)(fr + kc * 32);
        float4 f1 = *(const float4*)(fr + kc * 32 + 4);
        bf16x8 a;
        a[0] = (bf16_t)(f0.x * scale); a[1] = (bf16_t)(f0.y * scale);
        a[2] = (bf16_t)(f0.z * scale); a[3] = (bf16_t)(f0.w * scale);
        a[4] = (bf16_t)(f1.x * scale); a[5] = (bf16_t)(f1.y * scale);
        a[6] = (bf16_t)(f1.z * scale); a[7] = (bf16_t)(f1.w * scale);
        int kidx = (kc * 32 + ksel) >> 3;
#pragma unroll
        for (int jt = 0; jt < 8; ++jt) {
            int j = jt * 16 + (lane & 15);
            bf16x8 b = w1[j * 32 + kidx];
            acc[jt] = __builtin_amdgcn_mfma_f32_16x16x32_bf16(a, b, acc[jt], 0, 0, 0);
        }
    }
    int rbase = r0 + (lane >> 4) * 4;
#pragma unroll
    for (int jt = 0; jt < 8; ++jt) {
        int j = jt * 16 + (lane & 15);
#pragma unroll
        for (int r = 0; r < 4; ++r) {
            hp[(rbase + r) * 128 + j] = f_to_bf(acc[jt][r]);
        }
    }
}

// ---------------- layer-1 gather-aggregate + fused epilogue (bf16) ----------------
__global__ __launch_bounds__(256) void agg1_kernel(const int* __restrict__ row_start,
                                                   const int* __restrict__ deg_dst,
                                                   const ushort* __restrict__ es16,
                                                   const ushort* __restrict__ hp,
                                                   const float* __restrict__ dn_in,
                                                   const float* __restrict__ dn_out,
                                                   const float* __restrict__ b1,
                                                   ushort* __restrict__ h1s) {
    int wid = threadIdx.x >> 6;
    int lane = threadIdx.x & 63;
    int n = blockIdx.x * 4 + wid;
    if (n >= N_NODES) return;
    int beg = row_start[n];
    int len = deg_dst[n];
    int c = lane * 2;
    float ax = 0.f, ay = 0.f;
    int j = 0;
    for (; j + 1 < len; j += 2) {
        int s0 = es16[beg + j];
        int s1 = es16[beg + j + 1];
        uint v0 = *(const uint*)(hp + s0 * 128 + c);
        uint v1 = *(const uint*)(hp + s1 * 128 + c);
        ax += bflo_to_f(v0) + bflo_to_f(v1);
        ay += bfhi_to_f(v0) + bfhi_to_f(v1);
    }
    if (j < len) {
        uint v0 = *(const uint*)(hp + (int)es16[beg + j] * 128 + c);
        ax += bflo_to_f(v0);
        ay += bfhi_to_f(v0);
    }
    float dn_i = dn_in[n], dn_o = dn_out[n];
    float x0 = fmaxf(ax * dn_i + b1[c], 0.f) * dn_o;
    float x1 = fmaxf(ay * dn_i + b1[c + 1], 0.f) * dn_o;
    uint pk = (uint)f_to_bf(x0) | ((uint)f_to_bf(x1) << 16);
    *(uint*)(h1s + n * 128 + c) = pk;
}

// ---------------- GEMM2 (MFMA): hp2 = bf16( h1s @ W2 ) ----------------
__global__ __launch_bounds__(256) void gemm2_kernel(const ushort* __restrict__ h1s,
                                                    const ushort* __restrict__ W2T,
                                                    ushort* __restrict__ hp2) {
    int wave = (blockIdx.x * 256 + threadIdx.x) >> 6;
    if (wave >= 3125) return;
    int lane = threadIdx.x & 63;
    int r0 = wave * 16;
    int row = r0 + (lane & 15);
    const bf16x8* av = (const bf16x8*)(h1s + row * 128);
    const bf16x8* w2 = (const bf16x8*)W2T;

    f32x4 acc[2];
    acc[0] = (f32x4){0.f, 0.f, 0.f, 0.f};
    acc[1] = (f32x4){0.f, 0.f, 0.f, 0.f};
#pragma unroll
    for (int kc = 0; kc < 4; ++kc) {
        bf16x8 a = av[kc * 4 + (lane >> 4)];
#pragma unroll
        for (int jt = 0; jt < 2; ++jt) {
            int j = jt * 16 + (lane & 15);
            bf16x8 b = w2[j * 16 + kc * 4 + (lane >> 4)];
            acc[jt] = __builtin_amdgcn_mfma_f32_16x16x32_bf16(a, b, acc[jt], 0, 0, 0);
        }
    }
    int rbase = r0 + (lane >> 4) * 4;
#pragma unroll
    for (int jt = 0; jt < 2; ++jt) {
        int j = jt * 16 + (lane & 15);
#pragma unroll
        for (int r = 0; r < 4; ++r) {
            hp2[(rbase + r) * 32 + j] = f_to_bf(acc[jt][r]);
        }
    }
}

// ---------------- layer-2 gather-aggregate + bias + log_softmax ----------------
__global__ __launch_bounds__(256) void agg2lsm_kernel(const int* __restrict__ row_start,
                                                      const int* __restrict__ deg_dst,
                                                      const ushort* __restrict__ es16,
                                                      const ushort* __restrict__ hp2,
                                                      const float* __restrict__ dn_in,
                                                      const float* __restrict__ b2,
                                                      float* __restrict__ out) {
    int g = threadIdx.x >> 5;
    int lane = threadIdx.x & 31;
    int n = blockIdx.x * 8 + g;
    if (n >= N_NODES) return;
    int beg = row_start[n];
    int len = deg_dst[n];
    float acc = 0.f;
    int j = 0;
    for (; j + 1 < len; j += 2) {
        int s0 = es16[beg + j];
        int s1 = es16[beg + j + 1];
        acc += bflo_to_f((uint)hp2[s0 * 32 + lane]) + bflo_to_f((uint)hp2[s1 * 32 + lane]);
    }
    if (j < len) acc += bflo_to_f((uint)hp2[(int)es16[beg + j] * 32 + lane]);
    float x = acc * dn_in[n] + b2[lane];
    float mx = x;
    for (int m = 16; m; m >>= 1) mx = fmaxf(mx, __shfl_xor(mx, m, 32));
    float ex = expf(x - mx);
    float s = ex;
    for (int m = 16; m; m >>= 1) s += __shfl_xor(s, m, 32);
    out[n * 32 + lane] = x - mx - logf(s);
}

extern "C" void kernel_launch(void* const* d_in, const int* in_sizes, int n_in,
                              void* d_out, int out_size, void* d_ws, size_t ws_size,
                              hipStream_t stream) {
    const float* feat = (const float*)d_in[0];
    const int*   src  = (const int*)d_in[1];
    const int*   dst  = (const int*)d_in[2];
    const float* W1   = (const float*)d_in[3];
    const float* b1   = (const float*)d_in[4];
    const float* W2   = (const float*)d_in[5];
    const float* b2   = (const float*)d_in[6];
    float* out = (float*)d_out;

    // workspace layout, 4-byte units (all segment starts 16B-aligned)
    int*   iws       = (int*)d_ws;
    int*   cntd      = iws;                  // 8*50000 = 400000
    int*   cnts      = iws + 400000;         // 400000 -> ends 800000
    int*   deg_dst   = iws + 800000;         // 50000
    int*   row_start = iws + 850000;         // 50000
    int*   blocksum  = iws + 900000;         // 256
    int*   offs      = iws + 900256;         // 400000 -> ends 1300256
    ushort* d16      = (ushort*)(iws + 1300256);  // 800000 ushort -> ends 1700256
    ushort* s16      = (ushort*)(iws + 1700256);  // 800000 ushort -> ends 2100256
    ushort* es16     = (ushort*)(iws + 2100256);  // 800000 ushort -> ends 2500256
    float* fws       = (float*)d_ws;
    float* dn_out    = fws + 2500256;        // 50000
    float* dn_in     = fws + 2550256;        // 50000 -> ends 2600256
    ushort* W1T = (ushort*)(fws + 2600256);  // 32768 bf16 -> ends 2616640
    ushort* W2T = (ushort*)(fws + 2616640);  // 4096 bf16  -> ends 2618688
    ushort* hp  = (ushort*)(fws + 2618688);  // 6.4M bf16  -> ends 5818688
    ushort* h1s = (ushort*)(fws + 5818688);  // 6.4M bf16  -> ends 9018688
    ushort* hp2 = (ushort*)(fws + 9018688);  // 1.6M bf16  -> ends 9818688 (~39.3 MB)

    // zero replica histograms (cntd, cnts contiguous)
    hipMemsetAsync(cntd, 0, (size_t)800000 * sizeof(int), stream);

    pack_kernel<<<EB4, 256, 0, stream>>>(src, dst, s16, d16);
    hist_kernel<<<EB4, 256, 0, stream>>>(d16, s16, cntd, cnts);
    scan1_kernel<<<NB_SCAN, 256, 0, stream>>>(cntd, cnts, deg_dst, row_start, blocksum,
                                              dn_in, dn_out);
    scan2_kernel<<<1, 256, 0, stream>>>(blocksum);
    scan3_kernel<<<NB_SCAN, 256, 0, stream>>>(row_start, blocksum);
    offs_kernel<<<NB_SCAN, 256, 0, stream>>>(row_start, cntd, offs);
    fill_kernel<<<EB4, 256, 0, stream>>>(d16, s16, offs, es16);
    prep_w_kernel<<<128, 256, 0, stream>>>(W1, W2, W1T, W2T);

    gemm1_kernel<<<(3125 * 64 + 255) / 256, 256, 0, stream>>>(feat, W1T, dn_out, hp);
    agg1_kernel<<<(N_NODES + 3) / 4, 256, 0, stream>>>(row_start, deg_dst, es16,
                                                       hp, dn_in, dn_out, b1, h1s);
    gemm2_kernel<<<(3125 * 64 + 255) / 256, 256, 0, stream>>>(h1s, W2T, hp2);
    agg2lsm_kernel<<<(N_NODES + 7) / 8, 256, 0, stream>>>(row_start, deg_dst, es16,
                                                          hp2, dn_in, b2, out);
}

// Round 9
// 273.627 us; speedup vs baseline: 1.5779x; 1.2098x over previous
//
#include <hip/hip_runtime.h>
#include <hip/hip_bf16.h>

#define N_NODES 50000
#define N_EDGES 800000
#define NB_SCAN 196            // ceil(50000/256)
#define BH      64             // histogram/fill partition blocks per role
#define EDG_B   12500          // edges per partition block (64*12500 = 800000)
#define GRAN    3125           // int4 granules per block (EDG_B/4)
#define LDSW    25000          // LDS u32 words holding 50000 u16 counters

typedef __bf16 bf16_t;
typedef bf16_t bf16x8 __attribute__((ext_vector_type(8)));
typedef float  f32x4  __attribute__((ext_vector_type(4)));

static __device__ __forceinline__ float bfhi_to_f(uint v) {
    return __builtin_bit_cast(float, v & 0xffff0000u);
}
static __device__ __forceinline__ float bflo_to_f(uint v) {
    return __builtin_bit_cast(float, v << 16);
}
static __device__ __forceinline__ ushort f_to_bf(float x) {
    bf16_t q = (bf16_t)x;
    return __builtin_bit_cast(ushort, q);
}

// ---- fused: pack int32->u16, LDS partial histograms (no global atomics), W prep ----
// blocks [0,BH): dst role; [BH,2BH): src role; [2BH,2BH+6): weight bf16-transpose role
__global__ __launch_bounds__(512) void histpack_kernel(const int* __restrict__ src,
                                                       const int* __restrict__ dst,
                                                       const float* __restrict__ W1,
                                                       const float* __restrict__ W2,
                                                       ushort* __restrict__ s16,
                                                       ushort* __restrict__ d16,
                                                       ushort* __restrict__ Pd,
                                                       ushort* __restrict__ Ps,
                                                       ushort* __restrict__ W1T,
                                                       ushort* __restrict__ W2T) {
    __shared__ uint h[LDSW];
    int bid = blockIdx.x;
    int tid = threadIdx.x;
    if (bid >= 2 * BH) {
        int t = (bid - 2 * BH) * 512 + tid;
        for (int i = t; i < 32768; i += 6 * 512) {
            int j = i >> 8, k = i & 255;
            W1T[i] = f_to_bf(W1[k * 128 + j]);
        }
        for (int i = t; i < 4096; i += 6 * 512) {
            int j = i >> 7, k = i & 127;
            W2T[i] = f_to_bf(W2[k * 32 + j]);
        }
        return;
    }
    for (int i = tid; i < LDSW; i += 512) h[i] = 0;
    __syncthreads();
    bool is_dst = bid < BH;
    int part = is_dst ? bid : bid - BH;
    const int4* iv = (const int4*)((is_dst ? dst : src) + part * EDG_B);
    ushort* ov = (is_dst ? d16 : s16) + part * EDG_B;
    for (int g = tid; g < GRAN; g += 512) {
        int4 v = iv[g];
        ushort4 p;
        p.x = (ushort)v.x; p.y = (ushort)v.y; p.z = (ushort)v.z; p.w = (ushort)v.w;
        *(ushort4*)(ov + g * 4) = p;
        atomicAdd(&h[v.x >> 1], 1u << ((v.x & 1) * 16));
        atomicAdd(&h[v.y >> 1], 1u << ((v.y & 1) * 16));
        atomicAdd(&h[v.z >> 1], 1u << ((v.z & 1) * 16));
        atomicAdd(&h[v.w >> 1], 1u << ((v.w & 1) * 16));
    }
    __syncthreads();
    uint* P = (uint*)((is_dst ? Pd : Ps) + part * N_NODES);
    for (int i = tid; i < LDSW; i += 512) P[i] = h[i];
}

// ---- scan1: partial-reduce -> deg/norms, block-local exclusive scan ----
__global__ __launch_bounds__(256) void scan1_kernel(const ushort* __restrict__ Pd,
                                                    const ushort* __restrict__ Ps,
                                                    int* __restrict__ deg_dst,
                                                    int* __restrict__ row_start,
                                                    int* __restrict__ blocksum,
                                                    float* __restrict__ dn_in,
                                                    float* __restrict__ dn_out) {
    __shared__ int s[256];
    int i = blockIdx.x * 256 + threadIdx.x;
    int v = 0;
    if (i < N_NODES) {
        int u = 0;
        for (int b = 0; b < BH; ++b) {
            v += Pd[b * N_NODES + i];
            u += Ps[b * N_NODES + i];
        }
        deg_dst[i] = v;
        dn_in[i]  = 1.0f / sqrtf(fmaxf((float)v, 1.0f));
        dn_out[i] = 1.0f / sqrtf(fmaxf((float)u, 1.0f));
    }
    s[threadIdx.x] = v;
    __syncthreads();
    for (int off = 1; off < 256; off <<= 1) {
        int t = (threadIdx.x >= off) ? s[threadIdx.x - off] : 0;
        __syncthreads();
        s[threadIdx.x] += t;
        __syncthreads();
    }
    if (i < N_NODES) row_start[i] = s[threadIdx.x] - v;   // block-local exclusive
    if (threadIdx.x == 255) blocksum[blockIdx.x] = s[255];
}

// ---- scanfix: in-kernel scan of blocksums, finalize row_start, emit per-block offs ----
__global__ __launch_bounds__(256) void scanfix_offs_kernel(const int* __restrict__ blocksum,
                                                           const ushort* __restrict__ Pd,
                                                           int* __restrict__ row_start,
                                                           uint* __restrict__ offs) {
    __shared__ int bs[256];
    int v = (threadIdx.x < NB_SCAN) ? blocksum[threadIdx.x] : 0;
    bs[threadIdx.x] = v;
    __syncthreads();
    for (int off = 1; off < 256; off <<= 1) {    // inclusive scan
        int t = (threadIdx.x >= off) ? bs[threadIdx.x - off] : 0;
        __syncthreads();
        bs[threadIdx.x] += t;
        __syncthreads();
    }
    int add = (blockIdx.x > 0) ? bs[blockIdx.x - 1] : 0;
    int i = blockIdx.x * 256 + threadIdx.x;
    if (i >= N_NODES) return;
    int acc = row_start[i] + add;
    row_start[i] = acc;
    for (int b = 0; b < BH; ++b) {
        offs[b * N_NODES + i] = (uint)acc;
        acc += Pd[b * N_NODES + i];
    }
}

// ---- fill: LDS cursor ranks + pre-reserved per-block ranges (no global atomics) ----
__global__ __launch_bounds__(512) void fill_kernel(const ushort* __restrict__ d16,
                                                   const ushort* __restrict__ s16,
                                                   const uint* __restrict__ offs,
                                                   ushort* __restrict__ es16) {
    __shared__ uint lpos[LDSW];
    int tid = threadIdx.x, b = blockIdx.x;
    for (int i = tid; i < LDSW; i += 512) lpos[i] = 0;
    __syncthreads();
    const uint* of = offs + b * N_NODES;
    const ushort4* dv = (const ushort4*)(d16 + b * EDG_B);
    const ushort4* sv = (const ushort4*)(s16 + b * EDG_B);
#define FILL1(dd, ss) { int d_ = (int)(dd); uint sh_ = (uint)(d_ & 1) * 16; \
        uint old_ = atomicAdd(&lpos[d_ >> 1], 1u << sh_); \
        uint loc_ = (old_ >> sh_) & 0xffffu; \
        es16[of[d_] + loc_] = (ushort)(ss); }
    for (int g = tid; g < GRAN; g += 512) {
        ushort4 d4 = dv[g];
        ushort4 s4 = sv[g];
        FILL1(d4.x, s4.x);
        FILL1(d4.y, s4.y);
        FILL1(d4.z, s4.z);
        FILL1(d4.w, s4.w);
    }
#undef FILL1
}

// ---------------- GEMM1 (MFMA): hp = bf16( (feat*dn_out) @ W1 ) ----------------
__global__ __launch_bounds__(256) void gemm1_kernel(const float* __restrict__ feat,
                                                    const ushort* __restrict__ W1T,
                                                    const float* __restrict__ dn_out,
                                                    ushort* __restrict__ hp) {
    int wave = (blockIdx.x * 256 + threadIdx.x) >> 6;
    if (wave >= 3125) return;
    int lane = threadIdx.x & 63;
    int r0 = wave * 16;
    int row = r0 + (lane & 15);
    int ksel = (lane >> 4) * 8;
    float scale = dn_out[row];
    const float* fr = feat + row * 256 + ksel;
    const bf16x8* w1 = (const bf16x8*)W1T;

    f32x4 acc[8];
#pragma unroll
    for (int jt = 0; jt < 8; ++jt) acc[jt] = (f32x4){0.f, 0.f, 0.f, 0.f};

#pragma unroll
    for (int kc = 0; kc < 8; ++kc) {
        float4 f0 = *(const float4*)(fr + kc * 32);
        float4 f1 = *(const float4*)(fr + kc * 32 + 4);
        bf16x8 a;
        a[0] = (bf16_t)(f0.x * scale); a[1] = (bf16_t)(f0.y * scale);
        a[2] = (bf16_t)(f0.z * scale); a[3] = (bf16_t)(f0.w * scale);
        a[4] = (bf16_t)(f1.x * scale); a[5] = (bf16_t)(f1.y * scale);
        a[6] = (bf16_t)(f1.z * scale); a[7] = (bf16_t)(f1.w * scale);
        int kidx = (kc * 32 + ksel) >> 3;
#pragma unroll
        for (int jt = 0; jt < 8; ++jt) {
            int j = jt * 16 + (lane & 15);
            bf16x8 b = w1[j * 32 + kidx];
            acc[jt] = __builtin_amdgcn_mfma_f32_16x16x32_bf16(a, b, acc[jt], 0, 0, 0);
        }
    }
    int rbase = r0 + (lane >> 4) * 4;
#pragma unroll
    for (int jt = 0; jt < 8; ++jt) {
        int j = jt * 16 + (lane & 15);
#pragma unroll
        for (int r = 0; r < 4; ++r) {
            hp[(rbase + r) * 128 + j] = f_to_bf(acc[jt][r]);
        }
    }
}

// ---------------- layer-1 gather-aggregate + fused epilogue (bf16) ----------------
__global__ __launch_bounds__(256) void agg1_kernel(const int* __restrict__ row_start,
                                                   const int* __restrict__ deg_dst,
                                                   const ushort* __restrict__ es16,
                                                   const ushort* __restrict__ hp,
                                                   const float* __restrict__ dn_in,
                                                   const float* __restrict__ dn_out,
                                                   const float* __restrict__ b1,
                                                   ushort* __restrict__ h1s) {
    int wid = threadIdx.x >> 6;
    int lane = threadIdx.x & 63;
    int n = blockIdx.x * 4 + wid;
    if (n >= N_NODES) return;
    int beg = row_start[n];
    int len = deg_dst[n];
    int c = lane * 2;
    float ax = 0.f, ay = 0.f;
    int j = 0;
    for (; j + 1 < len; j += 2) {
        int s0 = es16[beg + j];
        int s1 = es16[beg + j + 1];
        uint v0 = *(const uint*)(hp + s0 * 128 + c);
        uint v1 = *(const uint*)(hp + s1 * 128 + c);
        ax += bflo_to_f(v0) + bflo_to_f(v1);
        ay += bfhi_to_f(v0) + bfhi_to_f(v1);
    }
    if (j < len) {
        uint v0 = *(const uint*)(hp + (int)es16[beg + j] * 128 + c);
        ax += bflo_to_f(v0);
        ay += bfhi_to_f(v0);
    }
    float dn_i = dn_in[n], dn_o = dn_out[n];
    float x0 = fmaxf(ax * dn_i + b1[c], 0.f) * dn_o;
    float x1 = fmaxf(ay * dn_i + b1[c + 1], 0.f) * dn_o;
    uint pk = (uint)f_to_bf(x0) | ((uint)f_to_bf(x1) << 16);
    *(uint*)(h1s + n * 128 + c) = pk;
}

// ---------------- GEMM2 (MFMA): hp2 = bf16( h1s @ W2 ) ----------------
__global__ __launch_bounds__(256) void gemm2_kernel(const ushort* __restrict__ h1s,
                                                    const ushort* __restrict__ W2T,
                                                    ushort* __restrict__ hp2) {
    int wave = (blockIdx.x * 256 + threadIdx.x) >> 6;
    if (wave >= 3125) return;
    int lane = threadIdx.x & 63;
    int r0 = wave * 16;
    int row = r0 + (lane & 15);
    const bf16x8* av = (const bf16x8*)(h1s + row * 128);
    const bf16x8* w2 = (const bf16x8*)W2T;

    f32x4 acc[2];
    acc[0] = (f32x4){0.f, 0.f, 0.f, 0.f};
    acc[1] = (f32x4){0.f, 0.f, 0.f, 0.f};
#pragma unroll
    for (int kc = 0; kc < 4; ++kc) {
        bf16x8 a = av[kc * 4 + (lane >> 4)];
#pragma unroll
        for (int jt = 0; jt < 2; ++jt) {
            int j = jt * 16 + (lane & 15);
            bf16x8 b = w2[j * 16 + kc * 4 + (lane >> 4)];
            acc[jt] = __builtin_amdgcn_mfma_f32_16x16x32_bf16(a, b, acc[jt], 0, 0, 0);
        }
    }
    int rbase = r0 + (lane >> 4) * 4;
#pragma unroll
    for (int jt = 0; jt < 2; ++jt) {
        int j = jt * 16 + (lane & 15);
#pragma unroll
        for (int r = 0; r < 4; ++r) {
            hp2[(rbase + r) * 32 + j] = f_to_bf(acc[jt][r]);
        }
    }
}

// ---------------- layer-2 gather-aggregate + bias + log_softmax ----------------
__global__ __launch_bounds__(256) void agg2lsm_kernel(const int* __restrict__ row_start,
                                                      const int* __restrict__ deg_dst,
                                                      const ushort* __restrict__ es16,
                                                      const ushort* __restrict__ hp2,
                                                      const float* __restrict__ dn_in,
                                                      const float* __restrict__ b2,
                                                      float* __restrict__ out) {
    int g = threadIdx.x >> 5;
    int lane = threadIdx.x & 31;
    int n = blockIdx.x * 8 + g;
    if (n >= N_NODES) return;
    int beg = row_start[n];
    int len = deg_dst[n];
    float acc = 0.f;
    int j = 0;
    for (; j + 1 < len; j += 2) {
        int s0 = es16[beg + j];
        int s1 = es16[beg + j + 1];
        acc += bflo_to_f((uint)hp2[s0 * 32 + lane]) + bflo_to_f((uint)hp2[s1 * 32 + lane]);
    }
    if (j < len) acc += bflo_to_f((uint)hp2[(int)es16[beg + j] * 32 + lane]);
    float x = acc * dn_in[n] + b2[lane];
    float mx = x;
    for (int m = 16; m; m >>= 1) mx = fmaxf(mx, __shfl_xor(mx, m, 32));
    float ex = expf(x - mx);
    float s = ex;
    for (int m = 16; m; m >>= 1) s += __shfl_xor(s, m, 32);
    out[n * 32 + lane] = x - mx - logf(s);
}

extern "C" void kernel_launch(void* const* d_in, const int* in_sizes, int n_in,
                              void* d_out, int out_size, void* d_ws, size_t ws_size,
                              hipStream_t stream) {
    const float* feat = (const float*)d_in[0];
    const int*   src  = (const int*)d_in[1];
    const int*   dst  = (const int*)d_in[2];
    const float* W1   = (const float*)d_in[3];
    const float* b1   = (const float*)d_in[4];
    const float* W2   = (const float*)d_in[5];
    const float* b2   = (const float*)d_in[6];
    float* out = (float*)d_out;

    // workspace layout, 4-byte units (all segment starts 16B-aligned)
    int*   iws       = (int*)d_ws;
    int*   deg_dst   = iws;                        // 50000
    int*   row_start = iws + 50000;                // 50000
    int*   blocksum  = iws + 100000;               // 256
    ushort* Pd       = (ushort*)(iws + 100256);    // 64*50000 u16 = 1.6M ints -> ends 1700256
    ushort* Ps       = (ushort*)(iws + 1700256);   // 1.6M ints -> ends 3300256
    uint*  offs      = (uint*)(iws + 3300256);     // 64*50000 u32 = 3.2M ints -> ends 6500256
    ushort* d16      = (ushort*)(iws + 6500256);   // 800000 u16 -> ends 6900256
    ushort* s16      = (ushort*)(iws + 6900256);   // 800000 u16 -> ends 7300256
    ushort* es16     = (ushort*)(iws + 7300256);   // 800000 u16 -> ends 7700256
    float* fws       = (float*)d_ws;
    float* dn_out    = fws + 7700256;              // 50000
    float* dn_in     = fws + 7750256;              // 50000 -> ends 7800256
    ushort* W1T = (ushort*)(fws + 7800256);        // 32768 bf16 -> ends 7816640
    ushort* W2T = (ushort*)(fws + 7816640);        // 4096 bf16  -> ends 7818688
    ushort* hp  = (ushort*)(fws + 7818688);        // 6.4M bf16  -> ends 11018688
    ushort* h1s = (ushort*)(fws + 11018688);       // 6.4M bf16  -> ends 14218688
    ushort* hp2 = (ushort*)(fws + 14218688);       // 1.6M bf16  -> ends 15018688 (~60.1 MB)

    histpack_kernel<<<2 * BH + 6, 512, 0, stream>>>(src, dst, W1, W2,
                                                    s16, d16, Pd, Ps, W1T, W2T);
    scan1_kernel<<<NB_SCAN, 256, 0, stream>>>(Pd, Ps, deg_dst, row_start, blocksum,
                                              dn_in, dn_out);
    scanfix_offs_kernel<<<NB_SCAN, 256, 0, stream>>>(blocksum, Pd, row_start, offs);
    fill_kernel<<<BH, 512, 0, stream>>>(d16, s16, offs, es16);

    gemm1_kernel<<<(3125 * 64 + 255) / 256, 256, 0, stream>>>(feat, W1T, dn_out, hp);
    agg1_kernel<<<(N_NODES + 3) / 4, 256, 0, stream>>>(row_start, deg_dst, es16,
                                                       hp, dn_in, dn_out, b1, h1s);
    gemm2_kernel<<<(3125 * 64 + 255) / 256, 256, 0, stream>>>(h1s, W2T, hp2);
    agg2lsm_kernel<<<(N_NODES + 7) / 8, 256, 0, stream>>>(row_start, deg_dst, es16,
                                                          hp2, dn_in, b2, out);
}

// Round 10
// 249.914 us; speedup vs baseline: 1.7276x; 1.0949x over previous
//
#include <hip/hip_runtime.h>
#include <hip/hip_bf16.h>

#define N_NODES 50000
#define N_EDGES 800000
#define NB_SCAN 196            // ceil(50000/256)
#define BH      64             // histogram/fill partition blocks per role
#define EDG_B   12500          // edges per partition block (64*12500 = 800000)
#define GRAN    3125           // int4 granules per block (EDG_B/4)
#define LDSW    25000          // LDS u32 words holding 50000 u16 counters

typedef __bf16 bf16_t;
typedef bf16_t bf16x8 __attribute__((ext_vector_type(8)));
typedef float  f32x4  __attribute__((ext_vector_type(4)));

static __device__ __forceinline__ float bfhi_to_f(uint v) {
    return __builtin_bit_cast(float, v & 0xffff0000u);
}
static __device__ __forceinline__ float bflo_to_f(uint v) {
    return __builtin_bit_cast(float, v << 16);
}
static __device__ __forceinline__ ushort f_to_bf(float x) {
    bf16_t q = (bf16_t)x;
    return __builtin_bit_cast(ushort, q);
}

// ---- fused: pack int32->u16, LDS partial histograms (no global atomics), W prep ----
// blocks [0,BH): dst role; [BH,2BH): src role; [2BH,2BH+6): weight bf16-transpose role
__global__ __launch_bounds__(512) void histpack_kernel(const int* __restrict__ src,
                                                       const int* __restrict__ dst,
                                                       const float* __restrict__ W1,
                                                       const float* __restrict__ W2,
                                                       ushort* __restrict__ s16,
                                                       ushort* __restrict__ d16,
                                                       ushort* __restrict__ Pd,
                                                       ushort* __restrict__ Ps,
                                                       ushort* __restrict__ W1T,
                                                       ushort* __restrict__ W2T) {
    __shared__ uint h[LDSW];
    int bid = blockIdx.x;
    int tid = threadIdx.x;
    if (bid >= 2 * BH) {
        int t = (bid - 2 * BH) * 512 + tid;
        for (int i = t; i < 32768; i += 6 * 512) {
            int j = i >> 8, k = i & 255;
            W1T[i] = f_to_bf(W1[k * 128 + j]);
        }
        for (int i = t; i < 4096; i += 6 * 512) {
            int j = i >> 7, k = i & 127;
            W2T[i] = f_to_bf(W2[k * 32 + j]);
        }
        return;
    }
    for (int i = tid; i < LDSW; i += 512) h[i] = 0;
    __syncthreads();
    bool is_dst = bid < BH;
    int part = is_dst ? bid : bid - BH;
    const int4* iv = (const int4*)((is_dst ? dst : src) + part * EDG_B);
    ushort* ov = (is_dst ? d16 : s16) + part * EDG_B;
    for (int g = tid; g < GRAN; g += 512) {
        int4 v = iv[g];
        ushort4 p;
        p.x = (ushort)v.x; p.y = (ushort)v.y; p.z = (ushort)v.z; p.w = (ushort)v.w;
        *(ushort4*)(ov + g * 4) = p;
        atomicAdd(&h[v.x >> 1], 1u << ((v.x & 1) * 16));
        atomicAdd(&h[v.y >> 1], 1u << ((v.y & 1) * 16));
        atomicAdd(&h[v.z >> 1], 1u << ((v.z & 1) * 16));
        atomicAdd(&h[v.w >> 1], 1u << ((v.w & 1) * 16));
    }
    __syncthreads();
    uint* P = (uint*)((is_dst ? Pd : Ps) + part * N_NODES);
    for (int i = tid; i < LDSW; i += 512) P[i] = h[i];
}

// ---- scan1: partial-reduce -> deg/norms, block-local exclusive scan ----
__global__ __launch_bounds__(256) void scan1_kernel(const ushort* __restrict__ Pd,
                                                    const ushort* __restrict__ Ps,
                                                    int* __restrict__ deg_dst,
                                                    int* __restrict__ row_start,
                                                    int* __restrict__ blocksum,
                                                    float* __restrict__ dn_in,
                                                    float* __restrict__ dn_out) {
    __shared__ int s[256];
    int i = blockIdx.x * 256 + threadIdx.x;
    int v = 0;
    if (i < N_NODES) {
        int u = 0;
        for (int b = 0; b < BH; ++b) {
            v += Pd[b * N_NODES + i];
            u += Ps[b * N_NODES + i];
        }
        deg_dst[i] = v;
        dn_in[i]  = 1.0f / sqrtf(fmaxf((float)v, 1.0f));
        dn_out[i] = 1.0f / sqrtf(fmaxf((float)u, 1.0f));
    }
    s[threadIdx.x] = v;
    __syncthreads();
    for (int off = 1; off < 256; off <<= 1) {
        int t = (threadIdx.x >= off) ? s[threadIdx.x - off] : 0;
        __syncthreads();
        s[threadIdx.x] += t;
        __syncthreads();
    }
    if (i < N_NODES) row_start[i] = s[threadIdx.x] - v;   // block-local exclusive
    if (threadIdx.x == 255) blocksum[blockIdx.x] = s[255];
}

// ---- scanfix: in-kernel scan of blocksums, finalize row_start, emit per-block offs ----
__global__ __launch_bounds__(256) void scanfix_offs_kernel(const int* __restrict__ blocksum,
                                                           const ushort* __restrict__ Pd,
                                                           int* __restrict__ row_start,
                                                           uint* __restrict__ offs) {
    __shared__ int bs[256];
    int v = (threadIdx.x < NB_SCAN) ? blocksum[threadIdx.x] : 0;
    bs[threadIdx.x] = v;
    __syncthreads();
    for (int off = 1; off < 256; off <<= 1) {    // inclusive scan
        int t = (threadIdx.x >= off) ? bs[threadIdx.x - off] : 0;
        __syncthreads();
        bs[threadIdx.x] += t;
        __syncthreads();
    }
    int add = (blockIdx.x > 0) ? bs[blockIdx.x - 1] : 0;
    int i = blockIdx.x * 256 + threadIdx.x;
    if (i >= N_NODES) return;
    int acc = row_start[i] + add;
    row_start[i] = acc;
    for (int b = 0; b < BH; ++b) {
        offs[b * N_NODES + i] = (uint)acc;
        acc += Pd[b * N_NODES + i];
    }
}

// ---- fill: LDS cursor ranks + pre-reserved per-block ranges (no global atomics) ----
__global__ __launch_bounds__(512) void fill_kernel(const ushort* __restrict__ d16,
                                                   const ushort* __restrict__ s16,
                                                   const uint* __restrict__ offs,
                                                   ushort* __restrict__ es16) {
    __shared__ uint lpos[LDSW];
    int tid = threadIdx.x, b = blockIdx.x;
    for (int i = tid; i < LDSW; i += 512) lpos[i] = 0;
    __syncthreads();
    const uint* of = offs + b * N_NODES;
    const ushort4* dv = (const ushort4*)(d16 + b * EDG_B);
    const ushort4* sv = (const ushort4*)(s16 + b * EDG_B);
#define FILL1(dd, ss) { int d_ = (int)(dd); uint sh_ = (uint)(d_ & 1) * 16; \
        uint old_ = atomicAdd(&lpos[d_ >> 1], 1u << sh_); \
        uint loc_ = (old_ >> sh_) & 0xffffu; \
        es16[of[d_] + loc_] = (ushort)(ss); }
    for (int g = tid; g < GRAN; g += 512) {
        ushort4 d4 = dv[g];
        ushort4 s4 = sv[g];
        FILL1(d4.x, s4.x);
        FILL1(d4.y, s4.y);
        FILL1(d4.z, s4.z);
        FILL1(d4.w, s4.w);
    }
#undef FILL1
}

// ---------------- GEMM1 (MFMA): hp = bf16( (feat*dn_out) @ W1 ) ----------------
__global__ __launch_bounds__(256) void gemm1_kernel(const float* __restrict__ feat,
                                                    const ushort* __restrict__ W1T,
                                                    const float* __restrict__ dn_out,
                                                    ushort* __restrict__ hp) {
    int wave = (blockIdx.x * 256 + threadIdx.x) >> 6;
    if (wave >= 3125) return;
    int lane = threadIdx.x & 63;
    int r0 = wave * 16;
    int row = r0 + (lane & 15);
    int ksel = (lane >> 4) * 8;
    float scale = dn_out[row];
    const float* fr = feat + row * 256 + ksel;
    const bf16x8* w1 = (const bf16x8*)W1T;

    f32x4 acc[8];
#pragma unroll
    for (int jt = 0; jt < 8; ++jt) acc[jt] = (f32x4){0.f, 0.f, 0.f, 0.f};

#pragma unroll
    for (int kc = 0; kc < 8; ++kc) {
        float4 f0 = *(const float4*)(fr + kc * 32);
        float4 f1 = *(const float4*)(fr + kc * 32 + 4);
        bf16x8 a;
        a[0] = (bf16_t)(f0.x * scale); a[1] = (bf16_t)(f0.y * scale);
        a[2] = (bf16_t)(f0.z * scale); a[3] = (bf16_t)(f0.w * scale);
        a[4] = (bf16_t)(f1.x * scale); a[5] = (bf16_t)(f1.y * scale);
        a[6] = (bf16_t)(f1.z * scale); a[7] = (bf16_t)(f1.w * scale);
        int kidx = (kc * 32 + ksel) >> 3;
#pragma unroll
        for (int jt = 0; jt < 8; ++jt) {
            int j = jt * 16 + (lane & 15);
            bf16x8 b = w1[j * 32 + kidx];
            acc[jt] = __builtin_amdgcn_mfma_f32_16x16x32_bf16(a, b, acc[jt], 0, 0, 0);
        }
    }
    int rbase = r0 + (lane >> 4) * 4;
#pragma unroll
    for (int jt = 0; jt < 8; ++jt) {
        int j = jt * 16 + (lane & 15);
#pragma unroll
        for (int r = 0; r < 4; ++r) {
            hp[(rbase + r) * 128 + j] = f_to_bf(acc[jt][r]);
        }
    }
}

// ---------------- layer-1 gather-aggregate, 8 loads in flight ----------------
__global__ __launch_bounds__(256) void agg1_kernel(const int* __restrict__ row_start,
                                                   const int* __restrict__ deg_dst,
                                                   const ushort* __restrict__ es16,
                                                   const ushort* __restrict__ hp,
                                                   const float* __restrict__ dn_in,
                                                   const float* __restrict__ dn_out,
                                                   const float* __restrict__ b1,
                                                   ushort* __restrict__ h1s) {
    int wid = threadIdx.x >> 6;
    int lane = threadIdx.x & 63;
    int n = blockIdx.x * 4 + wid;
    if (n >= N_NODES) return;
    int beg = row_start[n];
    int len = deg_dst[n];
    int c = lane * 2;
    const ushort* hb = hp + c;
    float ax = 0.f, ay = 0.f;
    int j = 0;
    for (; j + 7 < len; j += 8) {
        int i0 = es16[beg + j + 0], i1 = es16[beg + j + 1];
        int i2 = es16[beg + j + 2], i3 = es16[beg + j + 3];
        int i4 = es16[beg + j + 4], i5 = es16[beg + j + 5];
        int i6 = es16[beg + j + 6], i7 = es16[beg + j + 7];
        uint v0 = *(const uint*)(hb + i0 * 128);
        uint v1 = *(const uint*)(hb + i1 * 128);
        uint v2 = *(const uint*)(hb + i2 * 128);
        uint v3 = *(const uint*)(hb + i3 * 128);
        uint v4 = *(const uint*)(hb + i4 * 128);
        uint v5 = *(const uint*)(hb + i5 * 128);
        uint v6 = *(const uint*)(hb + i6 * 128);
        uint v7 = *(const uint*)(hb + i7 * 128);
        ax += ((bflo_to_f(v0) + bflo_to_f(v1)) + (bflo_to_f(v2) + bflo_to_f(v3)))
            + ((bflo_to_f(v4) + bflo_to_f(v5)) + (bflo_to_f(v6) + bflo_to_f(v7)));
        ay += ((bfhi_to_f(v0) + bfhi_to_f(v1)) + (bfhi_to_f(v2) + bfhi_to_f(v3)))
            + ((bfhi_to_f(v4) + bfhi_to_f(v5)) + (bfhi_to_f(v6) + bfhi_to_f(v7)));
    }
    for (; j + 1 < len; j += 2) {
        int i0 = es16[beg + j + 0], i1 = es16[beg + j + 1];
        uint v0 = *(const uint*)(hb + i0 * 128);
        uint v1 = *(const uint*)(hb + i1 * 128);
        ax += bflo_to_f(v0) + bflo_to_f(v1);
        ay += bfhi_to_f(v0) + bfhi_to_f(v1);
    }
    if (j < len) {
        uint v0 = *(const uint*)(hb + (int)es16[beg + j] * 128);
        ax += bflo_to_f(v0);
        ay += bfhi_to_f(v0);
    }
    float dn_i = dn_in[n], dn_o = dn_out[n];
    float x0 = fmaxf(ax * dn_i + b1[c], 0.f) * dn_o;
    float x1 = fmaxf(ay * dn_i + b1[c + 1], 0.f) * dn_o;
    uint pk = (uint)f_to_bf(x0) | ((uint)f_to_bf(x1) << 16);
    *(uint*)(h1s + n * 128 + c) = pk;
}

// ---------------- GEMM2 (MFMA): hp2 = bf16( h1s @ W2 ) ----------------
__global__ __launch_bounds__(256) void gemm2_kernel(const ushort* __restrict__ h1s,
                                                    const ushort* __restrict__ W2T,
                                                    ushort* __restrict__ hp2) {
    int wave = (blockIdx.x * 256 + threadIdx.x) >> 6;
    if (wave >= 3125) return;
    int lane = threadIdx.x & 63;
    int r0 = wave * 16;
    int row = r0 + (lane & 15);
    const bf16x8* av = (const bf16x8*)(h1s + row * 128);
    const bf16x8* w2 = (const bf16x8*)W2T;

    f32x4 acc[2];
    acc[0] = (f32x4){0.f, 0.f, 0.f, 0.f};
    acc[1] = (f32x4){0.f, 0.f, 0.f, 0.f};
#pragma unroll
    for (int kc = 0; kc < 4; ++kc) {
        bf16x8 a = av[kc * 4 + (lane >> 4)];
#pragma unroll
        for (int jt = 0; jt < 2; ++jt) {
            int j = jt * 16 + (lane & 15);
            bf16x8 b = w2[j * 16 + kc * 4 + (lane >> 4)];
            acc[jt] = __builtin_amdgcn_mfma_f32_16x16x32_bf16(a, b, acc[jt], 0, 0, 0);
        }
    }
    int rbase = r0 + (lane >> 4) * 4;
#pragma unroll
    for (int jt = 0; jt < 2; ++jt) {
        int j = jt * 16 + (lane & 15);
#pragma unroll
        for (int r = 0; r < 4; ++r) {
            hp2[(rbase + r) * 32 + j] = f_to_bf(acc[jt][r]);
        }
    }
}

// ---------------- layer-2 gather + bias + log_softmax, 8 loads in flight ----------------
__global__ __launch_bounds__(256) void agg2lsm_kernel(const int* __restrict__ row_start,
                                                      const int* __restrict__ deg_dst,
                                                      const ushort* __restrict__ es16,
                                                      const ushort* __restrict__ hp2,
                                                      const float* __restrict__ dn_in,
                                                      const float* __restrict__ b2,
                                                      float* __restrict__ out) {
    int g = threadIdx.x >> 5;
    int lane = threadIdx.x & 31;
    int n = blockIdx.x * 8 + g;
    if (n >= N_NODES) return;
    int beg = row_start[n];
    int len = deg_dst[n];
    const ushort* hb = hp2 + lane;
    float acc = 0.f;
    int j = 0;
    for (; j + 7 < len; j += 8) {
        int i0 = es16[beg + j + 0], i1 = es16[beg + j + 1];
        int i2 = es16[beg + j + 2], i3 = es16[beg + j + 3];
        int i4 = es16[beg + j + 4], i5 = es16[beg + j + 5];
        int i6 = es16[beg + j + 6], i7 = es16[beg + j + 7];
        float v0 = bflo_to_f((uint)hb[i0 * 32]);
        float v1 = bflo_to_f((uint)hb[i1 * 32]);
        float v2 = bflo_to_f((uint)hb[i2 * 32]);
        float v3 = bflo_to_f((uint)hb[i3 * 32]);
        float v4 = bflo_to_f((uint)hb[i4 * 32]);
        float v5 = bflo_to_f((uint)hb[i5 * 32]);
        float v6 = bflo_to_f((uint)hb[i6 * 32]);
        float v7 = bflo_to_f((uint)hb[i7 * 32]);
        acc += ((v0 + v1) + (v2 + v3)) + ((v4 + v5) + (v6 + v7));
    }
    for (; j + 1 < len; j += 2) {
        int i0 = es16[beg + j + 0], i1 = es16[beg + j + 1];
        acc += bflo_to_f((uint)hb[i0 * 32]) + bflo_to_f((uint)hb[i1 * 32]);
    }
    if (j < len) acc += bflo_to_f((uint)hb[(int)es16[beg + j] * 32]);
    float x = acc * dn_in[n] + b2[lane];
    float mx = x;
    for (int m = 16; m; m >>= 1) mx = fmaxf(mx, __shfl_xor(mx, m, 32));
    float ex = expf(x - mx);
    float s = ex;
    for (int m = 16; m; m >>= 1) s += __shfl_xor(s, m, 32);
    out[n * 32 + lane] = x - mx - logf(s);
}

extern "C" void kernel_launch(void* const* d_in, const int* in_sizes, int n_in,
                              void* d_out, int out_size, void* d_ws, size_t ws_size,
                              hipStream_t stream) {
    const float* feat = (const float*)d_in[0];
    const int*   src  = (const int*)d_in[1];
    const int*   dst  = (const int*)d_in[2];
    const float* W1   = (const float*)d_in[3];
    const float* b1   = (const float*)d_in[4];
    const float* W2   = (const float*)d_in[5];
    const float* b2   = (const float*)d_in[6];
    float* out = (float*)d_out;

    // workspace layout, 4-byte units (all segment starts 16B-aligned)
    int*   iws       = (int*)d_ws;
    int*   deg_dst   = iws;                        // 50000
    int*   row_start = iws + 50000;                // 50000
    int*   blocksum  = iws + 100000;               // 256
    ushort* Pd       = (ushort*)(iws + 100256);    // 64*50000 u16 = 1.6M ints -> ends 1700256
    ushort* Ps       = (ushort*)(iws + 1700256);   // 1.6M ints -> ends 3300256
    uint*  offs      = (uint*)(iws + 3300256);     // 64*50000 u32 = 3.2M ints -> ends 6500256
    ushort* d16      = (ushort*)(iws + 6500256);   // 800000 u16 -> ends 6900256
    ushort* s16      = (ushort*)(iws + 6900256);   // 800000 u16 -> ends 7300256
    ushort* es16     = (ushort*)(iws + 7300256);   // 800000 u16 -> ends 7700256
    float* fws       = (float*)d_ws;
    float* dn_out    = fws + 7700256;              // 50000
    float* dn_in     = fws + 7750256;              // 50000 -> ends 7800256
    ushort* W1T = (ushort*)(fws + 7800256);        // 32768 bf16 -> ends 7816640
    ushort* W2T = (ushort*)(fws + 7816640);        // 4096 bf16  -> ends 7818688
    ushort* hp  = (ushort*)(fws + 7818688);        // 6.4M bf16  -> ends 11018688
    ushort* h1s = (ushort*)(fws + 11018688);       // 6.4M bf16  -> ends 14218688
    ushort* hp2 = (ushort*)(fws + 14218688);       // 1.6M bf16  -> ends 15018688 (~60.1 MB)

    histpack_kernel<<<2 * BH + 6, 512, 0, stream>>>(src, dst, W1, W2,
                                                    s16, d16, Pd, Ps, W1T, W2T);
    scan1_kernel<<<NB_SCAN, 256, 0, stream>>>(Pd, Ps, deg_dst, row_start, blocksum,
                                              dn_in, dn_out);
    scanfix_offs_kernel<<<NB_SCAN, 256, 0, stream>>>(blocksum, Pd, row_start, offs);
    fill_kernel<<<BH, 512, 0, stream>>>(d16, s16, offs, es16);

    gemm1_kernel<<<(3125 * 64 + 255) / 256, 256, 0, stream>>>(feat, W1T, dn_out, hp);
    agg1_kernel<<<(N_NODES + 3) / 4, 256, 0, stream>>>(row_start, deg_dst, es16,
                                                       hp, dn_in, dn_out, b1, h1s);
    gemm2_kernel<<<(3125 * 64 + 255) / 256, 256, 0, stream>>>(h1s, W2T, hp2);
    agg2lsm_kernel<<<(N_NODES + 7) / 8, 256, 0, stream>>>(row_start, deg_dst, es16,
                                                          hp2, dn_in, b2, out);
}

// Round 11
// 241.617 us; speedup vs baseline: 1.7869x; 1.0343x over previous
//
#include <hip/hip_runtime.h>
#include <hip/hip_bf16.h>

#define N_NODES 50000
#define N_EDGES 800000
#define NB_SCAN 196            // ceil(50000/256)
#define BH      64             // histogram/fill partition blocks per role
#define EDG_B   12500          // edges per partition block (64*12500 = 800000)
#define GRAN    3125           // int4 granules per block (EDG_B/4)
#define LDSW    25000          // LDS u32 words holding 50000 u16 counters

typedef __bf16 bf16_t;
typedef bf16_t bf16x8 __attribute__((ext_vector_type(8)));
typedef float  f32x4  __attribute__((ext_vector_type(4)));

static __device__ __forceinline__ float bfhi_to_f(uint v) {
    return __builtin_bit_cast(float, v & 0xffff0000u);
}
static __device__ __forceinline__ float bflo_to_f(uint v) {
    return __builtin_bit_cast(float, v << 16);
}
static __device__ __forceinline__ ushort f_to_bf(float x) {
    bf16_t q = (bf16_t)x;
    return __builtin_bit_cast(ushort, q);
}

// ---- fused: pack int32->u16, LDS partial histograms (no global atomics), W prep ----
// blocks [0,BH): dst role; [BH,2BH): src role; [2BH,2BH+6): weight bf16-transpose role
__global__ __launch_bounds__(512) void histpack_kernel(const int* __restrict__ src,
                                                       const int* __restrict__ dst,
                                                       const float* __restrict__ W1,
                                                       const float* __restrict__ W2,
                                                       ushort* __restrict__ s16,
                                                       ushort* __restrict__ d16,
                                                       ushort* __restrict__ Pd,
                                                       ushort* __restrict__ Ps,
                                                       ushort* __restrict__ W1T,
                                                       ushort* __restrict__ W2T) {
    __shared__ uint h[LDSW];
    int bid = blockIdx.x;
    int tid = threadIdx.x;
    if (bid >= 2 * BH) {
        int t = (bid - 2 * BH) * 512 + tid;
        for (int i = t; i < 32768; i += 6 * 512) {
            int j = i >> 8, k = i & 255;
            W1T[i] = f_to_bf(W1[k * 128 + j]);
        }
        for (int i = t; i < 4096; i += 6 * 512) {
            int j = i >> 7, k = i & 127;
            W2T[i] = f_to_bf(W2[k * 32 + j]);
        }
        return;
    }
    for (int i = tid; i < LDSW; i += 512) h[i] = 0;
    __syncthreads();
    bool is_dst = bid < BH;
    int part = is_dst ? bid : bid - BH;
    const int4* iv = (const int4*)((is_dst ? dst : src) + part * EDG_B);
    ushort* ov = (is_dst ? d16 : s16) + part * EDG_B;
    for (int g = tid; g < GRAN; g += 512) {
        int4 v = iv[g];
        ushort4 p;
        p.x = (ushort)v.x; p.y = (ushort)v.y; p.z = (ushort)v.z; p.w = (ushort)v.w;
        *(ushort4*)(ov + g * 4) = p;
        atomicAdd(&h[v.x >> 1], 1u << ((v.x & 1) * 16));
        atomicAdd(&h[v.y >> 1], 1u << ((v.y & 1) * 16));
        atomicAdd(&h[v.z >> 1], 1u << ((v.z & 1) * 16));
        atomicAdd(&h[v.w >> 1], 1u << ((v.w & 1) * 16));
    }
    __syncthreads();
    uint* P = (uint*)((is_dst ? Pd : Ps) + part * N_NODES);
    for (int i = tid; i < LDSW; i += 512) P[i] = h[i];
}

// ---- scan1: partial-reduce -> deg/norms, block-local exclusive scan ----
__global__ __launch_bounds__(256) void scan1_kernel(const ushort* __restrict__ Pd,
                                                    const ushort* __restrict__ Ps,
                                                    int* __restrict__ deg_dst,
                                                    int* __restrict__ row_start,
                                                    int* __restrict__ blocksum,
                                                    float* __restrict__ dn_in,
                                                    float* __restrict__ dn_out) {
    __shared__ int s[256];
    int i = blockIdx.x * 256 + threadIdx.x;
    int v = 0;
    if (i < N_NODES) {
        int u = 0;
        for (int b = 0; b < BH; ++b) {
            v += Pd[b * N_NODES + i];
            u += Ps[b * N_NODES + i];
        }
        deg_dst[i] = v;
        dn_in[i]  = 1.0f / sqrtf(fmaxf((float)v, 1.0f));
        dn_out[i] = 1.0f / sqrtf(fmaxf((float)u, 1.0f));
    }
    s[threadIdx.x] = v;
    __syncthreads();
    for (int off = 1; off < 256; off <<= 1) {
        int t = (threadIdx.x >= off) ? s[threadIdx.x - off] : 0;
        __syncthreads();
        s[threadIdx.x] += t;
        __syncthreads();
    }
    if (i < N_NODES) row_start[i] = s[threadIdx.x] - v;   // block-local exclusive
    if (threadIdx.x == 255) blocksum[blockIdx.x] = s[255];
}

// ---- scanfix: in-kernel scan of blocksums, finalize row_start, emit per-block offs ----
__global__ __launch_bounds__(256) void scanfix_offs_kernel(const int* __restrict__ blocksum,
                                                           const ushort* __restrict__ Pd,
                                                           int* __restrict__ row_start,
                                                           uint* __restrict__ offs) {
    __shared__ int bs[256];
    int v = (threadIdx.x < NB_SCAN) ? blocksum[threadIdx.x] : 0;
    bs[threadIdx.x] = v;
    __syncthreads();
    for (int off = 1; off < 256; off <<= 1) {    // inclusive scan
        int t = (threadIdx.x >= off) ? bs[threadIdx.x - off] : 0;
        __syncthreads();
        bs[threadIdx.x] += t;
        __syncthreads();
    }
    int add = (blockIdx.x > 0) ? bs[blockIdx.x - 1] : 0;
    int i = blockIdx.x * 256 + threadIdx.x;
    if (i >= N_NODES) return;
    int acc = row_start[i] + add;
    row_start[i] = acc;
    for (int b = 0; b < BH; ++b) {
        offs[b * N_NODES + i] = (uint)acc;
        acc += Pd[b * N_NODES + i];
    }
}

// ---- fill: LDS cursor ranks + pre-reserved per-block ranges (no global atomics) ----
__global__ __launch_bounds__(512) void fill_kernel(const ushort* __restrict__ d16,
                                                   const ushort* __restrict__ s16,
                                                   const uint* __restrict__ offs,
                                                   ushort* __restrict__ es16) {
    __shared__ uint lpos[LDSW];
    int tid = threadIdx.x, b = blockIdx.x;
    for (int i = tid; i < LDSW; i += 512) lpos[i] = 0;
    __syncthreads();
    const uint* of = offs + b * N_NODES;
    const ushort4* dv = (const ushort4*)(d16 + b * EDG_B);
    const ushort4* sv = (const ushort4*)(s16 + b * EDG_B);
#define FILL1(dd, ss) { int d_ = (int)(dd); uint sh_ = (uint)(d_ & 1) * 16; \
        uint old_ = atomicAdd(&lpos[d_ >> 1], 1u << sh_); \
        uint loc_ = (old_ >> sh_) & 0xffffu; \
        es16[of[d_] + loc_] = (ushort)(ss); }
    for (int g = tid; g < GRAN; g += 512) {
        ushort4 d4 = dv[g];
        ushort4 s4 = sv[g];
        FILL1(d4.x, s4.x);
        FILL1(d4.y, s4.y);
        FILL1(d4.z, s4.z);
        FILL1(d4.w, s4.w);
    }
#undef FILL1
}

// ---------------- GEMM1 (MFMA, LDS-staged): hp = bf16( (feat*dn_out) @ W1 ) ----------------
// one block (4 waves) per 16-row strip; wave w handles column tiles {2w, 2w+1}.
__global__ __launch_bounds__(256) void gemm1_kernel(const float* __restrict__ feat,
                                                    const ushort* __restrict__ W1T,
                                                    const float* __restrict__ dn_out,
                                                    ushort* __restrict__ hp) {
    __shared__ ushort a_lds[16][256 + 8];   // +8 bf16 pad -> 528B row stride (2-way bank alias, free)
    int r0 = blockIdx.x * 16;
    int tid = threadIdx.x;
    // stage feat(16x256) * dn_out -> bf16 LDS; 1024 float4 granules, coalesced
    for (int g = tid; g < 1024; g += 256) {
        int row = g >> 6;
        int c4 = (g & 63) * 4;
        float4 f = *(const float4*)(feat + (r0 + row) * 256 + c4);
        float sc = dn_out[r0 + row];
        ushort4 q;
        q.x = f_to_bf(f.x * sc); q.y = f_to_bf(f.y * sc);
        q.z = f_to_bf(f.z * sc); q.w = f_to_bf(f.w * sc);
        *(ushort4*)&a_lds[row][c4] = q;
    }
    __syncthreads();
    int wid = tid >> 6;
    int lane = tid & 63;
    int l15 = lane & 15;
    int khalf = lane >> 4;           // 0..3
    const bf16x8* w1 = (const bf16x8*)W1T;
    f32x4 acc[2];
    acc[0] = (f32x4){0.f, 0.f, 0.f, 0.f};
    acc[1] = (f32x4){0.f, 0.f, 0.f, 0.f};
    int jt0 = wid * 2;
#pragma unroll
    for (int kc = 0; kc < 8; ++kc) {
        bf16x8 a = *(const bf16x8*)&a_lds[l15][kc * 32 + khalf * 8];
        int kidx = kc * 4 + khalf;
#pragma unroll
        for (int q = 0; q < 2; ++q) {
            int j = (jt0 + q) * 16 + l15;
            bf16x8 b = w1[j * 32 + kidx];
            acc[q] = __builtin_amdgcn_mfma_f32_16x16x32_bf16(a, b, acc[q], 0, 0, 0);
        }
    }
    int rbase = r0 + khalf * 4;
#pragma unroll
    for (int q = 0; q < 2; ++q) {
        int j = (jt0 + q) * 16 + l15;
#pragma unroll
        for (int r = 0; r < 4; ++r) {
            hp[(rbase + r) * 128 + j] = f_to_bf(acc[q][r]);
        }
    }
}

// ---------------- layer-1 gather-aggregate, 8 loads in flight ----------------
__global__ __launch_bounds__(256) void agg1_kernel(const int* __restrict__ row_start,
                                                   const int* __restrict__ deg_dst,
                                                   const ushort* __restrict__ es16,
                                                   const ushort* __restrict__ hp,
                                                   const float* __restrict__ dn_in,
                                                   const float* __restrict__ dn_out,
                                                   const float* __restrict__ b1,
                                                   ushort* __restrict__ h1s) {
    int wid = threadIdx.x >> 6;
    int lane = threadIdx.x & 63;
    int n = blockIdx.x * 4 + wid;
    if (n >= N_NODES) return;
    int beg = row_start[n];
    int len = deg_dst[n];
    int c = lane * 2;
    const ushort* hb = hp + c;
    float ax = 0.f, ay = 0.f;
    int j = 0;
    for (; j + 7 < len; j += 8) {
        int i0 = es16[beg + j + 0], i1 = es16[beg + j + 1];
        int i2 = es16[beg + j + 2], i3 = es16[beg + j + 3];
        int i4 = es16[beg + j + 4], i5 = es16[beg + j + 5];
        int i6 = es16[beg + j + 6], i7 = es16[beg + j + 7];
        uint v0 = *(const uint*)(hb + i0 * 128);
        uint v1 = *(const uint*)(hb + i1 * 128);
        uint v2 = *(const uint*)(hb + i2 * 128);
        uint v3 = *(const uint*)(hb + i3 * 128);
        uint v4 = *(const uint*)(hb + i4 * 128);
        uint v5 = *(const uint*)(hb + i5 * 128);
        uint v6 = *(const uint*)(hb + i6 * 128);
        uint v7 = *(const uint*)(hb + i7 * 128);
        ax += ((bflo_to_f(v0) + bflo_to_f(v1)) + (bflo_to_f(v2) + bflo_to_f(v3)))
            + ((bflo_to_f(v4) + bflo_to_f(v5)) + (bflo_to_f(v6) + bflo_to_f(v7)));
        ay += ((bfhi_to_f(v0) + bfhi_to_f(v1)) + (bfhi_to_f(v2) + bfhi_to_f(v3)))
            + ((bfhi_to_f(v4) + bfhi_to_f(v5)) + (bfhi_to_f(v6) + bfhi_to_f(v7)));
    }
    for (; j + 1 < len; j += 2) {
        int i0 = es16[beg + j + 0], i1 = es16[beg + j + 1];
        uint v0 = *(const uint*)(hb + i0 * 128);
        uint v1 = *(const uint*)(hb + i1 * 128);
        ax += bflo_to_f(v0) + bflo_to_f(v1);
        ay += bfhi_to_f(v0) + bfhi_to_f(v1);
    }
    if (j < len) {
        uint v0 = *(const uint*)(hb + (int)es16[beg + j] * 128);
        ax += bflo_to_f(v0);
        ay += bfhi_to_f(v0);
    }
    float dn_i = dn_in[n], dn_o = dn_out[n];
    float x0 = fmaxf(ax * dn_i + b1[c], 0.f) * dn_o;
    float x1 = fmaxf(ay * dn_i + b1[c + 1], 0.f) * dn_o;
    uint pk = (uint)f_to_bf(x0) | ((uint)f_to_bf(x1) << 16);
    *(uint*)(h1s + n * 128 + c) = pk;
}

// ---------------- GEMM2 (MFMA): hp2 = bf16( h1s @ W2 ) ----------------
__global__ __launch_bounds__(256) void gemm2_kernel(const ushort* __restrict__ h1s,
                                                    const ushort* __restrict__ W2T,
                                                    ushort* __restrict__ hp2) {
    int wave = (blockIdx.x * 256 + threadIdx.x) >> 6;
    if (wave >= 3125) return;
    int lane = threadIdx.x & 63;
    int r0 = wave * 16;
    int row = r0 + (lane & 15);
    const bf16x8* av = (const bf16x8*)(h1s + row * 128);
    const bf16x8* w2 = (const bf16x8*)W2T;

    f32x4 acc[2];
    acc[0] = (f32x4){0.f, 0.f, 0.f, 0.f};
    acc[1] = (f32x4){0.f, 0.f, 0.f, 0.f};
#pragma unroll
    for (int kc = 0; kc < 4; ++kc) {
        bf16x8 a = av[kc * 4 + (lane >> 4)];
#pragma unroll
        for (int jt = 0; jt < 2; ++jt) {
            int j = jt * 16 + (lane & 15);
            bf16x8 b = w2[j * 16 + kc * 4 + (lane >> 4)];
            acc[jt] = __builtin_amdgcn_mfma_f32_16x16x32_bf16(a, b, acc[jt], 0, 0, 0);
        }
    }
    int rbase = r0 + (lane >> 4) * 4;
#pragma unroll
    for (int jt = 0; jt < 2; ++jt) {
        int j = jt * 16 + (lane & 15);
#pragma unroll
        for (int r = 0; r < 4; ++r) {
            hp2[(rbase + r) * 32 + j] = f_to_bf(acc[jt][r]);
        }
    }
}

// ---------------- layer-2 gather + bias + log_softmax, 8 loads in flight ----------------
__global__ __launch_bounds__(256) void agg2lsm_kernel(const int* __restrict__ row_start,
                                                      const int* __restrict__ deg_dst,
                                                      const ushort* __restrict__ es16,
                                                      const ushort* __restrict__ hp2,
                                                      const float* __restrict__ dn_in,
                                                      const float* __restrict__ b2,
                                                      float* __restrict__ out) {
    int g = threadIdx.x >> 5;
    int lane = threadIdx.x & 31;
    int n = blockIdx.x * 8 + g;
    if (n >= N_NODES) return;
    int beg = row_start[n];
    int len = deg_dst[n];
    const ushort* hb = hp2 + lane;
    float acc = 0.f;
    int j = 0;
    for (; j + 7 < len; j += 8) {
        int i0 = es16[beg + j + 0], i1 = es16[beg + j + 1];
        int i2 = es16[beg + j + 2], i3 = es16[beg + j + 3];
        int i4 = es16[beg + j + 4], i5 = es16[beg + j + 5];
        int i6 = es16[beg + j + 6], i7 = es16[beg + j + 7];
        float v0 = bflo_to_f((uint)hb[i0 * 32]);
        float v1 = bflo_to_f((uint)hb[i1 * 32]);
        float v2 = bflo_to_f((uint)hb[i2 * 32]);
        float v3 = bflo_to_f((uint)hb[i3 * 32]);
        float v4 = bflo_to_f((uint)hb[i4 * 32]);
        float v5 = bflo_to_f((uint)hb[i5 * 32]);
        float v6 = bflo_to_f((uint)hb[i6 * 32]);
        float v7 = bflo_to_f((uint)hb[i7 * 32]);
        acc += ((v0 + v1) + (v2 + v3)) + ((v4 + v5) + (v6 + v7));
    }
    for (; j + 1 < len; j += 2) {
        int i0 = es16[beg + j + 0], i1 = es16[beg + j + 1];
        acc += bflo_to_f((uint)hb[i0 * 32]) + bflo_to_f((uint)hb[i1 * 32]);
    }
    if (j < len) acc += bflo_to_f((uint)hb[(int)es16[beg + j] * 32]);
    float x = acc * dn_in[n] + b2[lane];
    float mx = x;
    for (int m = 16; m; m >>= 1) mx = fmaxf(mx, __shfl_xor(mx, m, 32));
    float ex = expf(x - mx);
    float s = ex;
    for (int m = 16; m; m >>= 1) s += __shfl_xor(s, m, 32);
    out[n * 32 + lane] = x - mx - logf(s);
}

extern "C" void kernel_launch(void* const* d_in, const int* in_sizes, int n_in,
                              void* d_out, int out_size, void* d_ws, size_t ws_size,
                              hipStream_t stream) {
    const float* feat = (const float*)d_in[0];
    const int*   src  = (const int*)d_in[1];
    const int*   dst  = (const int*)d_in[2];
    const float* W1   = (const float*)d_in[3];
    const float* b1   = (const float*)d_in[4];
    const float* W2   = (const float*)d_in[5];
    const float* b2   = (const float*)d_in[6];
    float* out = (float*)d_out;

    // workspace layout, 4-byte units (all segment starts 16B-aligned)
    int*   iws       = (int*)d_ws;
    int*   deg_dst   = iws;                        // 50000
    int*   row_start = iws + 50000;                // 50000
    int*   blocksum  = iws + 100000;               // 256
    ushort* Pd       = (ushort*)(iws + 100256);    // 64*50000 u16 = 1.6M ints -> ends 1700256
    ushort* Ps       = (ushort*)(iws + 1700256);   // 1.6M ints -> ends 3300256
    uint*  offs      = (uint*)(iws + 3300256);     // 64*50000 u32 = 3.2M ints -> ends 6500256
    ushort* d16      = (ushort*)(iws + 6500256);   // 800000 u16 -> ends 6900256
    ushort* s16      = (ushort*)(iws + 6900256);   // 800000 u16 -> ends 7300256
    ushort* es16     = (ushort*)(iws + 7300256);   // 800000 u16 -> ends 7700256
    float* fws       = (float*)d_ws;
    float* dn_out    = fws + 7700256;              // 50000
    float* dn_in     = fws + 7750256;              // 50000 -> ends 7800256
    ushort* W1T = (ushort*)(fws + 7800256);        // 32768 bf16 -> ends 7816640
    ushort* W2T = (ushort*)(fws + 7816640);        // 4096 bf16  -> ends 7818688
    ushort* hp  = (ushort*)(fws + 7818688);        // 6.4M bf16  -> ends 11018688
    ushort* h1s = (ushort*)(fws + 11018688);       // 6.4M bf16  -> ends 14218688
    ushort* hp2 = (ushort*)(fws + 14218688);       // 1.6M bf16  -> ends 15018688 (~60.1 MB)

    histpack_kernel<<<2 * BH + 6, 512, 0, stream>>>(src, dst, W1, W2,
                                                    s16, d16, Pd, Ps, W1T, W2T);
    scan1_kernel<<<NB_SCAN, 256, 0, stream>>>(Pd, Ps, deg_dst, row_start, blocksum,
                                              dn_in, dn_out);
    scanfix_offs_kernel<<<NB_SCAN, 256, 0, stream>>>(blocksum, Pd, row_start, offs);
    fill_kernel<<<BH, 512, 0, stream>>>(d16, s16, offs, es16);

    gemm1_kernel<<<3125, 256, 0, stream>>>(feat, W1T, dn_out, hp);
    agg1_kernel<<<(N_NODES + 3) / 4, 256, 0, stream>>>(row_start, deg_dst, es16,
                                                       hp, dn_in, dn_out, b1, h1s);
    gemm2_kernel<<<(3125 * 64 + 255) / 256, 256, 0, stream>>>(h1s, W2T, hp2);
    agg2lsm_kernel<<<(N_NODES + 7) / 8, 256, 0, stream>>>(row_start, deg_dst, es16,
                                                          hp2, dn_in, b2, out);
}